// Round 10
// baseline (251.502 us; speedup 1.0000x reference)
//
#include <hip/hip_runtime.h>
#include <stdint.h>

#define N_TOKENS 32768
#define N_CODES  8192
#define DIM      256
#define EPSF     1e-8f

typedef __bf16 bf16x8 __attribute__((ext_vector_type(8)));
typedef float  f32x4  __attribute__((ext_vector_type(4)));
typedef unsigned short ushort8 __attribute__((ext_vector_type(8)));

// ws layout: [bf16 codebook, FRAGMENT ORDER, 4MiB][cnorm f32 32KiB][hist 32KiB]
#define WS_CNORM_OFF  (4u*1024u*1024u)
#define WS_HIST_OFF   (WS_CNORM_OFF + N_CODES*4u)

__device__ int g_ctr;   // k_argmin completion counter (zeroed by k_prep)

// ---------------------------------------------------------------------------
// K1: codebooks fp32 -> bf16 in MFMA-FRAGMENT ORDER, ||c||^2, zero hist. v15:
//  no LDS atomics — one WAVE per row-iter: wave w, iter i handles row 4w+i;
//  lane L loads float4 dims[4L..4L+4), full-wave shfl reduce -> cnorm.
//  Fragment store: lane L's ushort4 lands at
//    kc=L>>3, lq=(L>>1)&3, j=(L&1)*4:
//    byte = kc*1024 + (lq*16 + row)*16 + j*2.
// ---------------------------------------------------------------------------
__global__ __launch_bounds__(256) void k_prep(const float* __restrict__ cbf,
                                              unsigned short* __restrict__ cbh,
                                              float* __restrict__ cnorm,
                                              int* __restrict__ hist) {
    const int g    = blockIdx.x;        // code group 0..511 (16 codes each)
    const int tid  = threadIdx.x;
    const int w    = tid >> 6;
    const int lane = tid & 63;
    if (g < 32) hist[g * 256 + tid] = 0;
    if (g == 0 && tid == 0) g_ctr = 0;

    const int kc = lane >> 3;
    const int lq = (lane >> 1) & 3;
    const int jj = (lane & 1) * 4;

    #pragma unroll
    for (int i = 0; i < 4; ++i) {
        const int row = 4 * w + i;                      // 0..15
        const float4 v = ((const float4*)(cbf + (size_t)(g * 16 + row) * DIM))[lane];

        float sq = v.x * v.x + v.y * v.y + v.z * v.z + v.w * v.w;
        #pragma unroll
        for (int d = 1; d < 64; d <<= 1) sq += __shfl_xor(sq, d);
        if (lane == 0) cnorm[g * 16 + row] = sq;

        ushort4 u;
        u.x = __builtin_bit_cast(unsigned short, (__bf16)v.x);
        u.y = __builtin_bit_cast(unsigned short, (__bf16)v.y);
        u.z = __builtin_bit_cast(unsigned short, (__bf16)v.z);
        u.w = __builtin_bit_cast(unsigned short, (__bf16)v.w);
        *(ushort4*)((char*)cbh + (size_t)g * 8192 + kc * 1024 +
                    (lq * 16 + row) * 16 + jj * 2) = u;
    }
}

// ---------------------------------------------------------------------------
// K2: fused distance-matmul + argmax(x.c - cn/2) + quant + stats, v15.
//  v15 = EXACT v13 loop structure (proven 140us) + zero-pressure wins only.
//  v14 post-mortem: deferred-tail pairing grew live state -> scratch spills
//  -> spill vmem broke the hand-counted vmcnt discipline -> stale B data ->
//  histogram corrupted (output0's loose threshold hid it). Rule: never grow
//  live state inside an asm-counted loop.
//  Changes vs v13 (all zero-register):
//   - cn via LDS table cnS[8192] (loaded once at prologue): ds_read counts
//     lgkmcnt not vmcnt -> uniform 8-op vmem groups, WAITV = vmcnt(8);
//     cn global stream (64B/chunk/wave) gone.
//   - s_setprio(1) around the MFMA cluster (waves free-run -> T5 applies).
//   - k_stats merged via completion counter (v10-proven pattern).
// ---------------------------------------------------------------------------
__global__ __launch_bounds__(512, 2) void k_argmin(const float* __restrict__ X,
                                                   const float* __restrict__ R,
                                                   const unsigned short* __restrict__ cbh,
                                                   const float* __restrict__ cnorm,
                                                   float* __restrict__ out,
                                                   int* __restrict__ hist) {
    // layout: [0,69632) A-stage overlay (128 tok x 544B) — dead after prologue
    //         [69632,71680) redv[8][64] | [71680,73728) redi[8][64]
    //         [73728,74240) maxvS[128] | [74240,107008) cnS[8192] f32
    __shared__ __attribute__((aligned(16))) char smem[107008];
    __shared__ int amLast;
    float* redv  = (float*)(smem + 69632);
    int*   redi  = (int*)(smem + 71680);
    float* maxvS = (float*)(smem + 73728);
    float* cnS   = (float*)(smem + 74240);

    const int tid  = threadIdx.x;
    const int w    = tid >> 6;
    const int lane = tid & 63;
    const int lr   = lane & 15;
    const int lq   = lane >> 4;
    const int th   = w >> 2;          // token half
    const int wc   = w & 3;           // code quarter
    const int r0   = blockIdx.x * 128;
    const int mycol = wc * 16 + lr;

    // ---- A-stage: wave w loads tokens [16w,16w+16), row stride 544B ----
    {
        const float4* Xf4 = (const float4*)(X + (size_t)(r0 + 16 * w) * DIM);
        #pragma unroll
        for (int i = 0; i < 16; ++i) {
            const float4 v = Xf4[i * 64 + lane];
            ushort4 u;
            u.x = __builtin_bit_cast(unsigned short, (__bf16)v.x);
            u.y = __builtin_bit_cast(unsigned short, (__bf16)v.y);
            u.z = __builtin_bit_cast(unsigned short, (__bf16)v.z);
            u.w = __builtin_bit_cast(unsigned short, (__bf16)v.w);
            *(ushort4*)(smem + (16 * w + i) * 544 + lane * 8) = u;
        }
    }
    // ---- cnorm table -> LDS (8192 f32, coalesced float4) ----
    {
        float4* dst = (float4*)cnS;
        const float4* src = (const float4*)cnorm;
        #pragma unroll
        for (int i = 0; i < 4; ++i) dst[i * 512 + tid] = src[i * 512 + tid];
    }
    __syncthreads();

    bf16x8 A[4][8];
    #pragma unroll
    for (int mf = 0; mf < 4; ++mf)
        #pragma unroll
        for (int kc = 0; kc < 8; ++kc)
            A[mf][kc] = *(const bf16x8*)(smem + (64 * th + mf * 16 + lr) * 544 + kc * 64 + lq * 16);
    // nothing overwrites the A region or cnS during the loop; no barrier.
    // (the __syncthreads above drained all vmem, so at loop entry the only
    //  outstanding vmem is what we issue below — vmcnt counts are exact.)

    float maxv[16];
    int   maxi[16];
    #pragma unroll
    for (int i = 0; i < 16; ++i) { maxv[i] = -3.4e38f; maxi[i] = 0; }

    const unsigned int voff  = (unsigned int)(wc * 8192 + lane * 16);
    const unsigned int voff2 = voff + 4096u;

    bf16x8 bA[8], bB[8];

#define ISSUE_GRP(buf, chunk) do {                                                    \
    const unsigned short* gb_ = (const unsigned short*)((const char*)cbh +            \
                                                        (size_t)(chunk) * 32768);    \
    asm volatile("global_load_dwordx4 %0, %1, %2"             : "=v"(buf[0]) : "v"(voff),  "s"(gb_)); \
    asm volatile("global_load_dwordx4 %0, %1, %2 offset:1024" : "=v"(buf[1]) : "v"(voff),  "s"(gb_)); \
    asm volatile("global_load_dwordx4 %0, %1, %2 offset:2048" : "=v"(buf[2]) : "v"(voff),  "s"(gb_)); \
    asm volatile("global_load_dwordx4 %0, %1, %2 offset:3072" : "=v"(buf[3]) : "v"(voff),  "s"(gb_)); \
    asm volatile("global_load_dwordx4 %0, %1, %2"             : "=v"(buf[4]) : "v"(voff2), "s"(gb_)); \
    asm volatile("global_load_dwordx4 %0, %1, %2 offset:1024" : "=v"(buf[5]) : "v"(voff2), "s"(gb_)); \
    asm volatile("global_load_dwordx4 %0, %1, %2 offset:2048" : "=v"(buf[6]) : "v"(voff2), "s"(gb_)); \
    asm volatile("global_load_dwordx4 %0, %1, %2 offset:3072" : "=v"(buf[7]) : "v"(voff2), "s"(gb_)); \
} while (0)

#define WAITV8 do { asm volatile("s_waitcnt vmcnt(8)" ::: "memory");                  \
                    __builtin_amdgcn_sched_barrier(0); } while (0)
#define WAITV0 do { asm volatile("s_waitcnt vmcnt(0)" ::: "memory");                  \
                    __builtin_amdgcn_sched_barrier(0); } while (0)

#define COMPUTE_CHUNK(chunk, buf) do {                                                \
    const float cn_ = cnS[(chunk) * 64 + mycol];                                      \
    f32x4 acc_[4];                                                                    \
    _Pragma("unroll") for (int mf_ = 0; mf_ < 4; ++mf_) {                             \
        acc_[mf_][0] = 0.f; acc_[mf_][1] = 0.f; acc_[mf_][2] = 0.f; acc_[mf_][3] = 0.f; } \
    __builtin_amdgcn_s_setprio(1);                                                    \
    _Pragma("unroll") for (int kc_ = 0; kc_ < 8; ++kc_)                               \
        _Pragma("unroll") for (int mf_ = 0; mf_ < 4; ++mf_)                           \
            acc_[mf_] = __builtin_amdgcn_mfma_f32_16x16x32_bf16(A[mf_][kc_], buf[kc_],\
                                                                acc_[mf_], 0, 0, 0);  \
    __builtin_amdgcn_s_setprio(0);                                                    \
    const int col_ = (chunk) * 64 + mycol;                                            \
    _Pragma("unroll") for (int mf_ = 0; mf_ < 4; ++mf_)                               \
        _Pragma("unroll") for (int r_ = 0; r_ < 4; ++r_) {                            \
            const float v_ = fmaf(-0.5f, cn_, acc_[mf_][r_]);                         \
            const int j_ = mf_ * 4 + r_;                                              \
            if (v_ > maxv[j_]) { maxv[j_] = v_; maxi[j_] = col_; }                    \
        }                                                                             \
} while (0)

    // ---- prologue: 2 groups in flight ----
    ISSUE_GRP(bA, 0);
    ISSUE_GRP(bB, 1);

    // ---- steady state: always 2 groups outstanding; waits count, never drain
    for (int cc = 0; cc < 126; cc += 2) {
        WAITV8;                               // retire group cc (oldest 8)
        COMPUTE_CHUNK(cc, bA);
        ISSUE_GRP(bA, cc + 2);
        WAITV8;                               // retire group cc+1
        COMPUTE_CHUNK(cc + 1, bB);
        ISSUE_GRP(bB, cc + 3);
    }
    WAITV8;                                   // retire group 126
    COMPUTE_CHUNK(126, bA);
    WAITV0;                                   // retire group 127
    COMPUTE_CHUNK(127, bB);

#undef ISSUE_GRP
#undef WAITV8
#undef WAITV0
#undef COMPUTE_CHUNK

    // ---- reduce across the 16 lanes (lr) sharing each token row ----
    #pragma unroll
    for (int mf = 0; mf < 4; ++mf)
        #pragma unroll
        for (int r = 0; r < 4; ++r) {
            float v = maxv[mf * 4 + r]; int ix = maxi[mf * 4 + r];
            #pragma unroll
            for (int d = 1; d <= 8; d <<= 1) {
                const float ov = __shfl_xor(v, d);
                const int   oi = __shfl_xor(ix, d);
                if (ov > v || (ov == v && oi < ix)) { v = ov; ix = oi; }
            }
            if (lr == 0) {
                const int row = mf * 16 + lq * 4 + r;   // token row within half
                redv[w * 64 + row] = v; redi[w * 64 + row] = ix;
            }
        }
    __syncthreads();

    // ---- combine the 4 code-quarter waves per token; hist + maxvS ----
    if (tid < 128) {
        const int t = tid, tth = t >> 6, tl = t & 63;
        float v = redv[(4 * tth) * 64 + tl]; int ix = redi[(4 * tth) * 64 + tl];
        #pragma unroll
        for (int ww = 1; ww < 4; ++ww) {
            const float ov = redv[(4 * tth + ww) * 64 + tl];
            const int   oi = redi[(4 * tth + ww) * 64 + tl];
            if (ov > v || (ov == v && oi < ix)) { v = ov; ix = oi; }
        }
        maxvS[t] = v;
        atomicAdd(&hist[ix], 1);
    }
    __syncthreads();

    // ---- fused quant epilogue: wave w handles tokens [16w, 16w+16) ----
    for (int i = 0; i < 16; ++i) {
        const int tl = 16 * w + i;
        const int tok = r0 + tl;
        const float4 x = ((const float4*)(X + (size_t)tok * DIM))[lane];
        const float4 r = ((const float4*)(R + (size_t)tok * DIM))[lane];

        float x2 = x.x * x.x + x.y * x.y + x.z * x.z + x.w * x.w;
        float n2 = r.x * r.x + r.y * r.y + r.z * r.z + r.w * r.w;
        #pragma unroll
        for (int d = 1; d < 64; d <<= 1) {
            x2 += __shfl_xor(x2, d);
            n2 += __shfl_xor(n2, d);
        }
        const float mv = maxvS[tl];
        const float d2 = fmaxf(fmaf(-2.f, mv, x2), 0.f);
        const float s = sqrtf(d2) / (sqrtf(n2) + EPSF);

        float4 o;
        o.x = fmaf(s, r.x, x.x);
        o.y = fmaf(s, r.y, x.y);
        o.z = fmaf(s, r.z, x.z);
        o.w = fmaf(s, r.w, x.w);
        ((float4*)(out + (size_t)tok * DIM))[lane] = o;
    }

    // ---- merged stats: last-arriving block computes perplexity+unique ----
    if (tid == 0) {
        __threadfence();
        amLast = (atomicAdd(&g_ctr, 1) == (int)gridDim.x - 1);
    }
    __syncthreads();
    if (amLast) {
        __threadfence();   // acquire: make all blocks' hist atomics visible
        float s = 0.f; int u = 0;
        for (int b = tid; b < N_CODES; b += 512) {
            const int c = __hip_atomic_load(&hist[b], __ATOMIC_RELAXED,
                                            __HIP_MEMORY_SCOPE_AGENT);
            if (c > 0) ++u;
            const float p = (float)c * (1.f / (float)N_TOKENS);
            s += p * logf(p + EPSF);
        }
        #pragma unroll
        for (int d = 1; d < 64; d <<= 1) {
            s += __shfl_xor(s, d);
            u += __shfl_xor(u, d);
        }
        if (lane == 0) { redv[w] = s; redi[w] = u; }
        __syncthreads();
        if (tid == 0) {
            float st = 0.f; int ut = 0;
            #pragma unroll
            for (int i = 0; i < 8; ++i) { st += redv[i]; ut += redi[i]; }
            float* outs = out + (size_t)N_TOKENS * DIM;
            outs[0] = expf(-st);       // perplexity
            outs[1] = (float)ut;       // num_unique_indices
        }
    }
}

// ---------------------------------------------------------------------------
extern "C" void kernel_launch(void* const* d_in, const int* in_sizes, int n_in,
                              void* d_out, int out_size, void* d_ws, size_t ws_size,
                              hipStream_t stream) {
    const float* X = (const float*)d_in[0];  // input_data (32768,256)
    const float* R = (const float*)d_in[1];  // rand       (32768,256)
    const float* C = (const float*)d_in[2];  // codebooks  (8192,256)
    float* out = (float*)d_out;

    char* ws = (char*)d_ws;
    unsigned short* cbh = (unsigned short*)ws;             // fragment-order bf16 codebook
    float* cnorm = (float*)(ws + WS_CNORM_OFF);
    int*   hist  = (int*)(ws + WS_HIST_OFF);

    k_prep  <<<512,            256, 0, stream>>>(C, cbh, cnorm, hist);
    k_argmin<<<N_TOKENS / 128, 512, 0, stream>>>(X, R, cbh, cnorm, out, hist);
}

// Round 11
// 249.416 us; speedup vs baseline: 1.0084x; 1.0084x over previous
//
#include <hip/hip_runtime.h>
#include <stdint.h>

#define N_TOKENS 32768
#define N_CODES  8192
#define DIM      256
#define EPSF     1e-8f

typedef __bf16 bf16x8 __attribute__((ext_vector_type(8)));
typedef float  f32x4  __attribute__((ext_vector_type(4)));
typedef unsigned short ushort8 __attribute__((ext_vector_type(8)));

// ws layout: [bf16 codebook, FRAGMENT ORDER, 4MiB][cnorm f32 32KiB][hist 32KiB]
#define WS_CNORM_OFF  (4u*1024u*1024u)
#define WS_HIST_OFF   (WS_CNORM_OFF + N_CODES*4u)

__device__ int g_ctr;   // k_argmin completion counter (zeroed by k_prep)

// ---------------------------------------------------------------------------
// K1: codebooks fp32 -> bf16 in MFMA-FRAGMENT ORDER, ||c||^2, zero hist.
//  (v15's atomic-free version — passed R9.) One WAVE per row-iter: wave w,
//  iter i handles row 4w+i; lane L loads float4 dims[4L..4L+4), full-wave
//  shfl reduce -> cnorm. Fragment store: kc=L>>3, lq=(L>>1)&3, j=(L&1)*4:
//  byte = kc*1024 + (lq*16 + row)*16 + j*2.
// ---------------------------------------------------------------------------
__global__ __launch_bounds__(256) void k_prep(const float* __restrict__ cbf,
                                              unsigned short* __restrict__ cbh,
                                              float* __restrict__ cnorm,
                                              int* __restrict__ hist) {
    const int g    = blockIdx.x;        // code group 0..511 (16 codes each)
    const int tid  = threadIdx.x;
    const int w    = tid >> 6;
    const int lane = tid & 63;
    if (g < 32) hist[g * 256 + tid] = 0;
    if (g == 0 && tid == 0) g_ctr = 0;

    const int kc = lane >> 3;
    const int lq = (lane >> 1) & 3;
    const int jj = (lane & 1) * 4;

    #pragma unroll
    for (int i = 0; i < 4; ++i) {
        const int row = 4 * w + i;                      // 0..15
        const float4 v = ((const float4*)(cbf + (size_t)(g * 16 + row) * DIM))[lane];

        float sq = v.x * v.x + v.y * v.y + v.z * v.z + v.w * v.w;
        #pragma unroll
        for (int d = 1; d < 64; d <<= 1) sq += __shfl_xor(sq, d);
        if (lane == 0) cnorm[g * 16 + row] = sq;

        ushort4 u;
        u.x = __builtin_bit_cast(unsigned short, (__bf16)v.x);
        u.y = __builtin_bit_cast(unsigned short, (__bf16)v.y);
        u.z = __builtin_bit_cast(unsigned short, (__bf16)v.z);
        u.w = __builtin_bit_cast(unsigned short, (__bf16)v.w);
        *(ushort4*)((char*)cbh + (size_t)g * 8192 + kc * 1024 +
                    (lq * 16 + row) * 16 + jj * 2) = u;
    }
}

// ---------------------------------------------------------------------------
// K2: fused distance-matmul + argmax(x.c - cn/2) + quant + stats, v16.
//  v16 = EXACT v13 loop (proven 140us, correct twice) + merged stats only.
//  v15 post-mortem: setprio+sched fences around the MFMA cluster BLOCKED the
//  compiler's tail-into-MFMA-gap interleaving (m190: setprio null-to-neg on
//  GEMM-shaped loops), and the cn ds_read added an exposed lgkmcnt wait.
//  Both reverted: cn rides in the 9-op vmem group (oldest-first, vmcnt(9)
//  counted discipline), no setprio, no cn LDS table.
// ---------------------------------------------------------------------------
__global__ __launch_bounds__(512, 2) void k_argmin(const float* __restrict__ X,
                                                   const float* __restrict__ R,
                                                   const unsigned short* __restrict__ cbh,
                                                   const float* __restrict__ cnorm,
                                                   float* __restrict__ out,
                                                   int* __restrict__ hist) {
    // layout: [0,69632) A-stage overlay (128 tok x 544B) — dead after prologue
    //         [69632,71680) redv[8][64] | [71680,73728) redi[8][64]
    //         [73728,74240) maxvS[128]
    __shared__ __attribute__((aligned(16))) char smem[74240];
    __shared__ int amLast;
    float* redv  = (float*)(smem + 69632);
    int*   redi  = (int*)(smem + 71680);
    float* maxvS = (float*)(smem + 73728);

    const int tid  = threadIdx.x;
    const int w    = tid >> 6;
    const int lane = tid & 63;
    const int lr   = lane & 15;
    const int lq   = lane >> 4;
    const int th   = w >> 2;          // token half
    const int wc   = w & 3;           // code quarter
    const int r0   = blockIdx.x * 128;
    const int mycol = wc * 16 + lr;

    // ---- A-stage: wave w loads tokens [16w,16w+16), row stride 544B ----
    {
        const float4* Xf4 = (const float4*)(X + (size_t)(r0 + 16 * w) * DIM);
        #pragma unroll
        for (int i = 0; i < 16; ++i) {
            const float4 v = Xf4[i * 64 + lane];
            ushort4 u;
            u.x = __builtin_bit_cast(unsigned short, (__bf16)v.x);
            u.y = __builtin_bit_cast(unsigned short, (__bf16)v.y);
            u.z = __builtin_bit_cast(unsigned short, (__bf16)v.z);
            u.w = __builtin_bit_cast(unsigned short, (__bf16)v.w);
            *(ushort4*)(smem + (16 * w + i) * 544 + lane * 8) = u;
        }
    }
    __syncthreads();

    bf16x8 A[4][8];
    #pragma unroll
    for (int mf = 0; mf < 4; ++mf)
        #pragma unroll
        for (int kc = 0; kc < 8; ++kc)
            A[mf][kc] = *(const bf16x8*)(smem + (64 * th + mf * 16 + lr) * 544 + kc * 64 + lq * 16);
    // nothing overwrites the A region during the loop; no barrier needed.
    // (the __syncthreads above drained all vmem, so at loop entry the only
    //  outstanding vmem is what we issue below — vmcnt counts are exact.)

    float maxv[16];
    int   maxi[16];
    #pragma unroll
    for (int i = 0; i < 16; ++i) { maxv[i] = -3.4e38f; maxi[i] = 0; }

    const unsigned int voff  = (unsigned int)(wc * 8192 + lane * 16);
    const unsigned int voff2 = voff + 4096u;
    const unsigned int voffc = (unsigned int)(mycol * 4);

    bf16x8 bA[8], bB[8];
    float cnA, cnB;

#define ISSUE_GRP(buf, cnv, chunk) do {                                               \
    const unsigned short* gb_ = (const unsigned short*)((const char*)cbh +            \
                                                        (size_t)(chunk) * 32768);    \
    const float* cb_ = cnorm + (size_t)(chunk) * 64;                                  \
    asm volatile("global_load_dwordx4 %0, %1, %2"             : "=v"(buf[0]) : "v"(voff),  "s"(gb_)); \
    asm volatile("global_load_dwordx4 %0, %1, %2 offset:1024" : "=v"(buf[1]) : "v"(voff),  "s"(gb_)); \
    asm volatile("global_load_dwordx4 %0, %1, %2 offset:2048" : "=v"(buf[2]) : "v"(voff),  "s"(gb_)); \
    asm volatile("global_load_dwordx4 %0, %1, %2 offset:3072" : "=v"(buf[3]) : "v"(voff),  "s"(gb_)); \
    asm volatile("global_load_dwordx4 %0, %1, %2"             : "=v"(buf[4]) : "v"(voff2), "s"(gb_)); \
    asm volatile("global_load_dwordx4 %0, %1, %2 offset:1024" : "=v"(buf[5]) : "v"(voff2), "s"(gb_)); \
    asm volatile("global_load_dwordx4 %0, %1, %2 offset:2048" : "=v"(buf[6]) : "v"(voff2), "s"(gb_)); \
    asm volatile("global_load_dwordx4 %0, %1, %2 offset:3072" : "=v"(buf[7]) : "v"(voff2), "s"(gb_)); \
    asm volatile("global_load_dword %0, %1, %2"               : "=v"(cnv)    : "v"(voffc), "s"(cb_)); \
} while (0)

#define WAITV9 do { asm volatile("s_waitcnt vmcnt(9)" ::: "memory");                  \
                    __builtin_amdgcn_sched_barrier(0); } while (0)
#define WAITV0 do { asm volatile("s_waitcnt vmcnt(0)" ::: "memory");                  \
                    __builtin_amdgcn_sched_barrier(0); } while (0)

#define COMPUTE_CHUNK(chunk, buf, cnv) do {                                           \
    f32x4 acc_[4];                                                                    \
    _Pragma("unroll") for (int mf_ = 0; mf_ < 4; ++mf_) {                             \
        acc_[mf_][0] = 0.f; acc_[mf_][1] = 0.f; acc_[mf_][2] = 0.f; acc_[mf_][3] = 0.f; } \
    _Pragma("unroll") for (int kc_ = 0; kc_ < 8; ++kc_)                               \
        _Pragma("unroll") for (int mf_ = 0; mf_ < 4; ++mf_)                           \
            acc_[mf_] = __builtin_amdgcn_mfma_f32_16x16x32_bf16(A[mf_][kc_], buf[kc_],\
                                                                acc_[mf_], 0, 0, 0);  \
    const int col_ = (chunk) * 64 + mycol;                                            \
    _Pragma("unroll") for (int mf_ = 0; mf_ < 4; ++mf_)                               \
        _Pragma("unroll") for (int r_ = 0; r_ < 4; ++r_) {                            \
            const float v_ = fmaf(-0.5f, (cnv), acc_[mf_][r_]);                       \
            const int j_ = mf_ * 4 + r_;                                              \
            if (v_ > maxv[j_]) { maxv[j_] = v_; maxi[j_] = col_; }                    \
        }                                                                             \
} while (0)

    // ---- prologue: 2 groups in flight ----
    ISSUE_GRP(bA, cnA, 0);
    ISSUE_GRP(bB, cnB, 1);

    // ---- steady state: always 2 groups outstanding; waits count, never drain
    for (int cc = 0; cc < 126; cc += 2) {
        WAITV9;                               // retire group cc (oldest 9)
        COMPUTE_CHUNK(cc, bA, cnA);
        ISSUE_GRP(bA, cnA, cc + 2);
        WAITV9;                               // retire group cc+1
        COMPUTE_CHUNK(cc + 1, bB, cnB);
        ISSUE_GRP(bB, cnB, cc + 3);
    }
    WAITV9;                                   // retire group 126
    COMPUTE_CHUNK(126, bA, cnA);
    WAITV0;                                   // retire group 127
    COMPUTE_CHUNK(127, bB, cnB);

#undef ISSUE_GRP
#undef WAITV9
#undef WAITV0
#undef COMPUTE_CHUNK

    // ---- reduce across the 16 lanes (lr) sharing each token row ----
    #pragma unroll
    for (int mf = 0; mf < 4; ++mf)
        #pragma unroll
        for (int r = 0; r < 4; ++r) {
            float v = maxv[mf * 4 + r]; int ix = maxi[mf * 4 + r];
            #pragma unroll
            for (int d = 1; d <= 8; d <<= 1) {
                const float ov = __shfl_xor(v, d);
                const int   oi = __shfl_xor(ix, d);
                if (ov > v || (ov == v && oi < ix)) { v = ov; ix = oi; }
            }
            if (lr == 0) {
                const int row = mf * 16 + lq * 4 + r;   // token row within half
                redv[w * 64 + row] = v; redi[w * 64 + row] = ix;
            }
        }
    __syncthreads();

    // ---- combine the 4 code-quarter waves per token; hist + maxvS ----
    if (tid < 128) {
        const int t = tid, tth = t >> 6, tl = t & 63;
        float v = redv[(4 * tth) * 64 + tl]; int ix = redi[(4 * tth) * 64 + tl];
        #pragma unroll
        for (int ww = 1; ww < 4; ++ww) {
            const float ov = redv[(4 * tth + ww) * 64 + tl];
            const int   oi = redi[(4 * tth + ww) * 64 + tl];
            if (ov > v || (ov == v && oi < ix)) { v = ov; ix = oi; }
        }
        maxvS[t] = v;
        atomicAdd(&hist[ix], 1);
    }
    __syncthreads();

    // ---- fused quant epilogue: wave w handles tokens [16w, 16w+16) ----
    for (int i = 0; i < 16; ++i) {
        const int tl = 16 * w + i;
        const int tok = r0 + tl;
        const float4 x = ((const float4*)(X + (size_t)tok * DIM))[lane];
        const float4 r = ((const float4*)(R + (size_t)tok * DIM))[lane];

        float x2 = x.x * x.x + x.y * x.y + x.z * x.z + x.w * x.w;
        float n2 = r.x * r.x + r.y * r.y + r.z * r.z + r.w * r.w;
        #pragma unroll
        for (int d = 1; d < 64; d <<= 1) {
            x2 += __shfl_xor(x2, d);
            n2 += __shfl_xor(n2, d);
        }
        const float mv = maxvS[tl];
        const float d2 = fmaxf(fmaf(-2.f, mv, x2), 0.f);
        const float s = sqrtf(d2) / (sqrtf(n2) + EPSF);

        float4 o;
        o.x = fmaf(s, r.x, x.x);
        o.y = fmaf(s, r.y, x.y);
        o.z = fmaf(s, r.z, x.z);
        o.w = fmaf(s, r.w, x.w);
        ((float4*)(out + (size_t)tok * DIM))[lane] = o;
    }

    // ---- merged stats: last-arriving block computes perplexity+unique ----
    if (tid == 0) {
        __threadfence();
        amLast = (atomicAdd(&g_ctr, 1) == (int)gridDim.x - 1);
    }
    __syncthreads();
    if (amLast) {
        __threadfence();   // acquire: make all blocks' hist atomics visible
        float s = 0.f; int u = 0;
        for (int b = tid; b < N_CODES; b += 512) {
            const int c = __hip_atomic_load(&hist[b], __ATOMIC_RELAXED,
                                            __HIP_MEMORY_SCOPE_AGENT);
            if (c > 0) ++u;
            const float p = (float)c * (1.f / (float)N_TOKENS);
            s += p * logf(p + EPSF);
        }
        #pragma unroll
        for (int d = 1; d < 64; d <<= 1) {
            s += __shfl_xor(s, d);
            u += __shfl_xor(u, d);
        }
        if (lane == 0) { redv[w] = s; redi[w] = u; }
        __syncthreads();
        if (tid == 0) {
            float st = 0.f; int ut = 0;
            #pragma unroll
            for (int i = 0; i < 8; ++i) { st += redv[i]; ut += redi[i]; }
            float* outs = out + (size_t)N_TOKENS * DIM;
            outs[0] = expf(-st);       // perplexity
            outs[1] = (float)ut;       // num_unique_indices
        }
    }
}

// ---------------------------------------------------------------------------
extern "C" void kernel_launch(void* const* d_in, const int* in_sizes, int n_in,
                              void* d_out, int out_size, void* d_ws, size_t ws_size,
                              hipStream_t stream) {
    const float* X = (const float*)d_in[0];  // input_data (32768,256)
    const float* R = (const float*)d_in[1];  // rand       (32768,256)
    const float* C = (const float*)d_in[2];  // codebooks  (8192,256)
    float* out = (float*)d_out;

    char* ws = (char*)d_ws;
    unsigned short* cbh = (unsigned short*)ws;             // fragment-order bf16 codebook
    float* cnorm = (float*)(ws + WS_CNORM_OFF);
    int*   hist  = (int*)(ws + WS_HIST_OFF);

    k_prep  <<<512,            256, 0, stream>>>(C, cbh, cnorm, hist);
    k_argmin<<<N_TOKENS / 128, 512, 0, stream>>>(X, R, cbh, cnorm, out, hist);
}

// Round 12
// 232.906 us; speedup vs baseline: 1.0798x; 1.0709x over previous
//
#include <hip/hip_runtime.h>
#include <stdint.h>

#define N_TOKENS 32768
#define N_CODES  8192
#define DIM      256
#define EPSF     1e-8f

typedef __bf16 bf16x8 __attribute__((ext_vector_type(8)));
typedef float  f32x4  __attribute__((ext_vector_type(4)));
typedef unsigned short ushort8 __attribute__((ext_vector_type(8)));

// ws layout: [bf16 codebook, FRAGMENT ORDER, 4MiB][cnorm f32 32KiB][hist 32KiB]
#define WS_CNORM_OFF  (4u*1024u*1024u)
#define WS_HIST_OFF   (WS_CNORM_OFF + N_CODES*4u)

// ---------------------------------------------------------------------------
// K1: codebooks fp32 -> bf16 in MFMA-FRAGMENT ORDER, ||c||^2, zero hist.
//  Fragment layout: group g = cc*4 + q (16 codes), within group:
//    byte offset = kc*1024 + lane*16,  lane = lq*16 + lr
//    holds code row (g*16 + lr), dims [kc*32 + lq*8, +8) as 8 bf16.
//  (R7-proven version, verbatim. Do NOT swap this writer: the session's
//   R9-R10 regression tracked bundled k_prep/stats changes — rule #19.)
// ---------------------------------------------------------------------------
__global__ __launch_bounds__(256) void k_prep(const float* __restrict__ cbf,
                                              unsigned short* __restrict__ cbh,
                                              float* __restrict__ cnorm,
                                              int* __restrict__ hist) {
    const int g   = blockIdx.x;        // code group 0..511 (16 codes each)
    const int tid = threadIdx.x;
    if (g < 32) hist[g * 256 + tid] = 0;

    __shared__ float nrm[16];
    if (tid < 16) nrm[tid] = 0.f;
    __syncthreads();

    #pragma unroll
    for (int i = 0; i < 2; ++i) {
        const int e  = i * 256 + tid;          // 0..511
        const int kc = e >> 6;
        const int ln = e & 63;
        const int lq = ln >> 4, lr = ln & 15;
        const float* src = cbf + ((size_t)(g * 16 + lr)) * DIM + kc * 32 + lq * 8;
        const float4 v0 = ((const float4*)src)[0];
        const float4 v1 = ((const float4*)src)[1];

        ushort8 u;
        u[0] = __builtin_bit_cast(unsigned short, (__bf16)v0.x);
        u[1] = __builtin_bit_cast(unsigned short, (__bf16)v0.y);
        u[2] = __builtin_bit_cast(unsigned short, (__bf16)v0.z);
        u[3] = __builtin_bit_cast(unsigned short, (__bf16)v0.w);
        u[4] = __builtin_bit_cast(unsigned short, (__bf16)v1.x);
        u[5] = __builtin_bit_cast(unsigned short, (__bf16)v1.y);
        u[6] = __builtin_bit_cast(unsigned short, (__bf16)v1.z);
        u[7] = __builtin_bit_cast(unsigned short, (__bf16)v1.w);
        *(ushort8*)((char*)cbh + (size_t)g * 8192 + kc * 1024 + ln * 16) = u;

        const float p = v0.x*v0.x + v0.y*v0.y + v0.z*v0.z + v0.w*v0.w
                      + v1.x*v1.x + v1.y*v1.y + v1.z*v1.z + v1.w*v1.w;
        atomicAdd(&nrm[lr], p);
    }
    __syncthreads();
    if (tid < 16) cnorm[g * 16 + tid] = nrm[tid];
}

// ---------------------------------------------------------------------------
// K2: fused distance-matmul + argmax(x.c - cn/2) + quant epilogue, v13.
//  (R7-proven source, verbatim — session best: argmin 140-147us, total 234.6.)
//  Register-direct fragment-ordered B + asm counted-vmcnt pipeline:
//   - per chunk ONE 9-op vmem group (8x dwordx4 B-frags + 1x dword cn),
//     SGPR base + 32-bit voffset, imm offsets.
//   - steady state: 2 groups (18 ops) outstanding; `s_waitcnt vmcnt(9)`
//     retires exactly the group about to be consumed. vmcnt(0) only at end.
//   - sched_barrier(0) after every wait (rule #18).
//  NOTE: kernel sits at EXACTLY 256 combined regs/wave (VGPR 128 + AGPRs).
//  Any added live state or epilogue code perturbs the loop (v14 spilled ->
//  corrupt; v15/v16 merged-stats tail cost +19us via regalloc). Treat the
//  whole kernel as frozen unless the change REDUCES register pressure.
// ---------------------------------------------------------------------------
__global__ __launch_bounds__(512, 2) void k_argmin(const float* __restrict__ X,
                                                   const float* __restrict__ R,
                                                   const unsigned short* __restrict__ cbh,
                                                   const float* __restrict__ cnorm,
                                                   float* __restrict__ out,
                                                   int* __restrict__ hist) {
    // layout: [0,69632) A-stage overlay (128 tok x 544B) — dead after prologue
    //         [69632,71680) redv[8][64] | [71680,73728) redi[8][64]
    //         [73728,74240) maxvS[128]
    __shared__ __attribute__((aligned(16))) char smem[74240];
    float* redv  = (float*)(smem + 69632);
    int*   redi  = (int*)(smem + 71680);
    float* maxvS = (float*)(smem + 73728);

    const int tid  = threadIdx.x;
    const int w    = tid >> 6;
    const int lane = tid & 63;
    const int lr   = lane & 15;
    const int lq   = lane >> 4;
    const int th   = w >> 2;          // token half
    const int wc   = w & 3;           // code quarter
    const int r0   = blockIdx.x * 128;
    const int mycol = wc * 16 + lr;

    // ---- A-stage: wave w loads tokens [16w,16w+16), row stride 544B ----
    {
        const float4* Xf4 = (const float4*)(X + (size_t)(r0 + 16 * w) * DIM);
        #pragma unroll
        for (int i = 0; i < 16; ++i) {
            const float4 v = Xf4[i * 64 + lane];
            ushort4 u;
            u.x = __builtin_bit_cast(unsigned short, (__bf16)v.x);
            u.y = __builtin_bit_cast(unsigned short, (__bf16)v.y);
            u.z = __builtin_bit_cast(unsigned short, (__bf16)v.z);
            u.w = __builtin_bit_cast(unsigned short, (__bf16)v.w);
            *(ushort4*)(smem + (16 * w + i) * 544 + lane * 8) = u;
        }
    }
    __syncthreads();

    bf16x8 A[4][8];
    #pragma unroll
    for (int mf = 0; mf < 4; ++mf)
        #pragma unroll
        for (int kc = 0; kc < 8; ++kc)
            A[mf][kc] = *(const bf16x8*)(smem + (64 * th + mf * 16 + lr) * 544 + kc * 64 + lq * 16);
    // nothing overwrites the A region during the loop; no barrier needed.
    // (compiler waits vmcnt(0)+lgkmcnt(0) at the __syncthreads above, so at
    //  loop entry the ONLY outstanding vmem is what we issue below.)

    float maxv[16];
    int   maxi[16];
    #pragma unroll
    for (int i = 0; i < 16; ++i) { maxv[i] = -3.4e38f; maxi[i] = 0; }

    // per-lane voffsets for the fragment-ordered codebook:
    //   group base (SGPR) = cbh + chunk*32768 ; voff = wc*8192 + lane*16
    const unsigned int voff  = (unsigned int)(wc * 8192 + lane * 16);
    const unsigned int voff2 = voff + 4096u;
    const unsigned int voffc = (unsigned int)(mycol * 4);

    bf16x8 bA[8], bB[8];
    float cnA, cnB;

#define ISSUE_GRP(buf, cnv, chunk) do {                                               \
    const unsigned short* gb_ = (const unsigned short*)((const char*)cbh +            \
                                                        (size_t)(chunk) * 32768);    \
    const float* cb_ = cnorm + (size_t)(chunk) * 64;                                  \
    asm volatile("global_load_dwordx4 %0, %1, %2"             : "=v"(buf[0]) : "v"(voff),  "s"(gb_)); \
    asm volatile("global_load_dwordx4 %0, %1, %2 offset:1024" : "=v"(buf[1]) : "v"(voff),  "s"(gb_)); \
    asm volatile("global_load_dwordx4 %0, %1, %2 offset:2048" : "=v"(buf[2]) : "v"(voff),  "s"(gb_)); \
    asm volatile("global_load_dwordx4 %0, %1, %2 offset:3072" : "=v"(buf[3]) : "v"(voff),  "s"(gb_)); \
    asm volatile("global_load_dwordx4 %0, %1, %2"             : "=v"(buf[4]) : "v"(voff2), "s"(gb_)); \
    asm volatile("global_load_dwordx4 %0, %1, %2 offset:1024" : "=v"(buf[5]) : "v"(voff2), "s"(gb_)); \
    asm volatile("global_load_dwordx4 %0, %1, %2 offset:2048" : "=v"(buf[6]) : "v"(voff2), "s"(gb_)); \
    asm volatile("global_load_dwordx4 %0, %1, %2 offset:3072" : "=v"(buf[7]) : "v"(voff2), "s"(gb_)); \
    asm volatile("global_load_dword %0, %1, %2"               : "=v"(cnv)    : "v"(voffc), "s"(cb_)); \
} while (0)

#define WAITV9 do { asm volatile("s_waitcnt vmcnt(9)" ::: "memory");                  \
                    __builtin_amdgcn_sched_barrier(0); } while (0)
#define WAITV0 do { asm volatile("s_waitcnt vmcnt(0)" ::: "memory");                  \
                    __builtin_amdgcn_sched_barrier(0); } while (0)

#define COMPUTE_CHUNK(chunk, buf, cnv) do {                                           \
    f32x4 acc_[4];                                                                    \
    _Pragma("unroll") for (int mf_ = 0; mf_ < 4; ++mf_) {                             \
        acc_[mf_][0] = 0.f; acc_[mf_][1] = 0.f; acc_[mf_][2] = 0.f; acc_[mf_][3] = 0.f; } \
    _Pragma("unroll") for (int kc_ = 0; kc_ < 8; ++kc_)                               \
        _Pragma("unroll") for (int mf_ = 0; mf_ < 4; ++mf_)                           \
            acc_[mf_] = __builtin_amdgcn_mfma_f32_16x16x32_bf16(A[mf_][kc_], buf[kc_],\
                                                                acc_[mf_], 0, 0, 0);  \
    const int col_ = (chunk) * 64 + mycol;                                            \
    _Pragma("unroll") for (int mf_ = 0; mf_ < 4; ++mf_)                               \
        _Pragma("unroll") for (int r_ = 0; r_ < 4; ++r_) {                            \
            const float v_ = fmaf(-0.5f, (cnv), acc_[mf_][r_]);                       \
            const int j_ = mf_ * 4 + r_;                                              \
            if (v_ > maxv[j_]) { maxv[j_] = v_; maxi[j_] = col_; }                    \
        }                                                                             \
} while (0)

    // ---- prologue: 2 groups in flight ----
    ISSUE_GRP(bA, cnA, 0);
    ISSUE_GRP(bB, cnB, 1);

    // ---- steady state: always 2 groups outstanding; waits count, never drain
    for (int cc = 0; cc < 126; cc += 2) {
        WAITV9;                               // retire group cc (oldest 9)
        COMPUTE_CHUNK(cc, bA, cnA);
        ISSUE_GRP(bA, cnA, cc + 2);
        WAITV9;                               // retire group cc+1
        COMPUTE_CHUNK(cc + 1, bB, cnB);
        ISSUE_GRP(bB, cnB, cc + 3);
    }
    WAITV9;                                   // retire group 126
    COMPUTE_CHUNK(126, bA, cnA);
    WAITV0;                                   // retire group 127
    COMPUTE_CHUNK(127, bB, cnB);

#undef ISSUE_GRP
#undef WAITV9
#undef WAITV0
#undef COMPUTE_CHUNK

    // ---- reduce across the 16 lanes (lr) sharing each token row ----
    #pragma unroll
    for (int mf = 0; mf < 4; ++mf)
        #pragma unroll
        for (int r = 0; r < 4; ++r) {
            float v = maxv[mf * 4 + r]; int ix = maxi[mf * 4 + r];
            #pragma unroll
            for (int d = 1; d <= 8; d <<= 1) {
                const float ov = __shfl_xor(v, d);
                const int   oi = __shfl_xor(ix, d);
                if (ov > v || (ov == v && oi < ix)) { v = ov; ix = oi; }
            }
            if (lr == 0) {
                const int row = mf * 16 + lq * 4 + r;   // token row within half
                redv[w * 64 + row] = v; redi[w * 64 + row] = ix;
            }
        }
    __syncthreads();

    // ---- combine the 4 code-quarter waves per token; hist + maxvS ----
    if (tid < 128) {
        const int t = tid, tth = t >> 6, tl = t & 63;
        float v = redv[(4 * tth) * 64 + tl]; int ix = redi[(4 * tth) * 64 + tl];
        #pragma unroll
        for (int ww = 1; ww < 4; ++ww) {
            const float ov = redv[(4 * tth + ww) * 64 + tl];
            const int   oi = redi[(4 * tth + ww) * 64 + tl];
            if (ov > v || (ov == v && oi < ix)) { v = ov; ix = oi; }
        }
        maxvS[t] = v;
        atomicAdd(&hist[ix], 1);
    }
    __syncthreads();

    // ---- fused quant epilogue: wave w handles tokens [16w, 16w+16) ----
    for (int i = 0; i < 16; ++i) {
        const int tl = 16 * w + i;
        const int tok = r0 + tl;
        const float4 x = ((const float4*)(X + (size_t)tok * DIM))[lane];
        const float4 r = ((const float4*)(R + (size_t)tok * DIM))[lane];

        float x2 = x.x * x.x + x.y * x.y + x.z * x.z + x.w * x.w;
        float n2 = r.x * r.x + r.y * r.y + r.z * r.z + r.w * r.w;
        #pragma unroll
        for (int d = 1; d < 64; d <<= 1) {
            x2 += __shfl_xor(x2, d);
            n2 += __shfl_xor(n2, d);
        }
        const float mv = maxvS[tl];
        const float d2 = fmaxf(fmaf(-2.f, mv, x2), 0.f);
        const float s = sqrtf(d2) / (sqrtf(n2) + EPSF);

        float4 o;
        o.x = fmaf(s, r.x, x.x);
        o.y = fmaf(s, r.y, x.y);
        o.z = fmaf(s, r.z, x.z);
        o.w = fmaf(s, r.w, x.w);
        ((float4*)(out + (size_t)tok * DIM))[lane] = o;
    }
}

// ---------------------------------------------------------------------------
// K3: perplexity + num_unique from histogram. single block, 1024 thr.
// ---------------------------------------------------------------------------
__global__ __launch_bounds__(1024) void k_stats(const int* __restrict__ hist,
                                                float* __restrict__ outs) {
    float s = 0.f; int u = 0;
    for (int b = threadIdx.x; b < N_CODES; b += 1024) {
        const float c = (float)hist[b];
        if (c > 0.f) ++u;
        const float p = c * (1.f / (float)N_TOKENS);
        s += p * logf(p + EPSF);
    }
    #pragma unroll
    for (int d = 1; d < 64; d <<= 1) {
        s += __shfl_xor(s, d);
        u += __shfl_xor(u, d);
    }
    __shared__ float ss[16];
    __shared__ int   su[16];
    const int w = threadIdx.x >> 6, lane = threadIdx.x & 63;
    if (lane == 0) { ss[w] = s; su[w] = u; }
    __syncthreads();
    if (threadIdx.x == 0) {
        float st = 0.f; int ut = 0;
        #pragma unroll
        for (int i = 0; i < 16; ++i) { st += ss[i]; ut += su[i]; }
        outs[0] = expf(-st);       // perplexity
        outs[1] = (float)ut;       // num_unique_indices
    }
}

// ---------------------------------------------------------------------------
extern "C" void kernel_launch(void* const* d_in, const int* in_sizes, int n_in,
                              void* d_out, int out_size, void* d_ws, size_t ws_size,
                              hipStream_t stream) {
    const float* X = (const float*)d_in[0];  // input_data (32768,256)
    const float* R = (const float*)d_in[1];  // rand       (32768,256)
    const float* C = (const float*)d_in[2];  // codebooks  (8192,256)
    float* out = (float*)d_out;

    char* ws = (char*)d_ws;
    unsigned short* cbh = (unsigned short*)ws;             // fragment-order bf16 codebook
    float* cnorm = (float*)(ws + WS_CNORM_OFF);
    int*   hist  = (int*)(ws + WS_HIST_OFF);

    k_prep  <<<512,            256, 0, stream>>>(C, cbh, cnorm, hist);
    k_argmin<<<N_TOKENS / 128, 512, 0, stream>>>(X, R, cbh, cnorm, out, hist);
    k_stats <<<1, 1024, 0, stream>>>(hist, out + (size_t)N_TOKENS * DIM);
}